// Round 1
// baseline (110.304 us; speedup 1.0000x reference)
//
#include <hip/hip_runtime.h>

#define FIELD 39
#define DIM 16
#define CROSS 741
#define BATCH 8192

// One wave handles 4 rows: lane = rloc*16 + d.  Each lane keeps all 39 field
// embeddings for its (row, dim) in registers; pair loop fully unrolled so the
// e[] array stays in VGPRs (no dynamic indexing -> no scratch).
__global__ __launch_bounds__(256) void fwfm_kernel(
    const int*   __restrict__ inputs,   // [BATCH][FIELD] int32
    const float* __restrict__ emb,      // [1M][DIM]
    const float* __restrict__ fw,       // [CROSS]
    const float* __restrict__ lw,       // [1M]
    const float* __restrict__ bias,     // [1]
    float*       __restrict__ out)      // [BATCH]
{
    const int tid  = threadIdx.x;
    const int lane = tid & 63;
    const int wave = tid >> 6;
    const int d    = lane & 15;       // dim owned by this lane
    const int rloc = lane >> 4;       // row within wave (0..3)
    const int row  = blockIdx.x * 16 + wave * 4 + rloc;   // grid=512 -> rows 0..8191

    const int* rowIdx = inputs + row * FIELD;

    // ---- load indices (compile-time f -> stays in registers) ----
    int idxv[FIELD];
    #pragma unroll
    for (int f = 0; f < FIELD; ++f) idxv[f] = rowIdx[f];

    // ---- gather embeddings: 16 consecutive lanes read one contiguous 64B row ----
    float e[FIELD];
    #pragma unroll
    for (int f = 0; f < FIELD; ++f)
        e[f] = emb[(size_t)idxv[f] * DIM + d];

    // ---- first order: lanes split the 39 fields by d (reload idx from cache,
    //      avoids runtime-indexing the register array) ----
    float fo = lw[rowIdx[d]] + lw[rowIdx[d + 16]];
    if (d + 32 < FIELD) fo += lw[rowIdx[d + 32]];

    // ---- second order:  sum_i e_i * (sum_{j>i} fw_p * e_j)  ----
    float acc = 0.f;
    int p = 0;
    #pragma unroll
    for (int i = 0; i < FIELD - 1; ++i) {
        float inner = 0.f;
        #pragma unroll
        for (int j = i + 1; j < FIELD; ++j) {
            inner = fmaf(fw[p], e[j], inner);   // fw[p]: uniform, const offset -> s_load
            ++p;
        }
        acc = fmaf(e[i], inner, acc);
    }

    // ---- reduce the 16 dim-lanes of this row ----
    float tot = fo + acc;
    tot += __shfl_xor(tot, 1, 64);
    tot += __shfl_xor(tot, 2, 64);
    tot += __shfl_xor(tot, 4, 64);
    tot += __shfl_xor(tot, 8, 64);

    if (d == 0) out[row] = tot + bias[0];
}

extern "C" void kernel_launch(void* const* d_in, const int* in_sizes, int n_in,
                              void* d_out, int out_size, void* d_ws, size_t ws_size,
                              hipStream_t stream) {
    const int*   inputs = (const int*)  d_in[0];
    const float* emb    = (const float*)d_in[1];
    const float* fw     = (const float*)d_in[2];
    const float* lw     = (const float*)d_in[3];
    const float* bias   = (const float*)d_in[4];
    float*       out    = (float*)      d_out;

    dim3 grid(BATCH / 16);   // 512 blocks * (256 threads = 4 waves * 4 rows) = 8192 rows
    fwfm_kernel<<<grid, 256, 0, stream>>>(inputs, emb, fw, lw, bias, out);
}